// Round 1
// baseline (88.138 us; speedup 1.0000x reference)
//
#include <hip/hip_runtime.h>
#include <cfloat>
#include <cstddef>

// Problem constants (fixed by setup_inputs): B=32, n=512, H=768, k=5 (k<=MAXK supported)
#define NB 32
#define NN 512
#define NH 768
#define H4 (NH / 4)        // 192 float4 per encI row
#define ROWS (NB * NN)     // 16384
#define MAXK 8
#define INF_C 3000.0f
#define SELF_D 9000000.0f  // INF*INF self-distance

// ---------------------------------------------------------------------------
// Kernel 1: adjusted box centers. center = ((s0+s2)/2, (s1+s3)/2) + INF if masked-out.
// Non-fused f32 ops to match numpy/jax f32 rounding as closely as possible.
// ---------------------------------------------------------------------------
__global__ void centers_kernel(const float* __restrict__ sp, const int* __restrict__ mask,
                               float2* __restrict__ ctr) {
  int t = blockIdx.x * blockDim.x + threadIdx.x;
  if (t >= ROWS) return;
  const float* s = sp + (size_t)t * 6;
  float cx = __fmul_rn(__fadd_rn(s[0], s[2]), 0.5f);
  float cy = __fmul_rn(__fadd_rn(s[1], s[3]), 0.5f);
  if (mask[t] == 0) { cx = __fadd_rn(cx, INF_C); cy = __fadd_rn(cy, INF_C); }
  ctr[t] = make_float2(cx, cy);
}

// ---------------------------------------------------------------------------
// Kernel 2a: partial per-batch row sums of encI. 16 chunks x 32 rows each.
// part layout: [(b*16 + chunk)][h4]  (float4)
// ---------------------------------------------------------------------------
__global__ void rowsum_part_kernel(const float4* __restrict__ e4, float4* __restrict__ part) {
  int t = blockIdx.x * blockDim.x + threadIdx.x;  // NB*16*H4 = 98304 threads
  int h4 = t % H4;
  int bc = t / H4;
  int b = bc >> 4, chunk = bc & 15;
  const float4* p = e4 + ((size_t)(b * NN + chunk * 32)) * H4 + h4;
  float ax = 0.f, ay = 0.f, az = 0.f, aw = 0.f;
#pragma unroll 4
  for (int r = 0; r < 32; ++r) {
    float4 v = p[(size_t)r * H4];
    ax += v.x; ay += v.y; az += v.z; aw += v.w;
  }
  part[t] = make_float4(ax, ay, az, aw);
}

// Kernel 2b: reduce the 16 chunk-partials -> S[b][h4]
__global__ void rowsum_reduce_kernel(const float4* __restrict__ part, float4* __restrict__ S4) {
  int t = blockIdx.x * blockDim.x + threadIdx.x;  // NB*H4 = 6144 threads
  int h4 = t % H4;
  int b = t / H4;
  float ax = 0.f, ay = 0.f, az = 0.f, aw = 0.f;
#pragma unroll
  for (int c = 0; c < 16; ++c) {
    float4 v = part[(size_t)(b * 16 + c) * H4 + h4];
    ax += v.x; ay += v.y; az += v.z; aw += v.w;
  }
  S4[t] = make_float4(ax, ay, az, aw);
}

// ---------------------------------------------------------------------------
// Kernel 3: top-k nearest (smallest distance, ties -> smallest index, self=9e6).
// One wave (64 lanes) per row; each lane owns 8 candidates (j = c*64+lane).
// k extraction rounds of lexicographic wave-argmin. Matches jax.lax.top_k order.
// ---------------------------------------------------------------------------
__global__ __launch_bounds__(256) void topk_kernel(const float2* __restrict__ ctr,
                                                   const int* __restrict__ kptr,
                                                   unsigned short* __restrict__ idxout) {
  int wid = threadIdx.x >> 6;
  int lane = threadIdx.x & 63;
  int row = blockIdx.x * 4 + wid;
  int b = row >> 9;
  int i = row & (NN - 1);
  int k = *kptr; if (k > MAXK) k = MAXK; if (k < 0) k = 0;

  float2 ci = ctr[row];
  float dv[8];
#pragma unroll
  for (int c = 0; c < 8; ++c) {
    int j = c * 64 + lane;
    float2 cj = ctr[b * NN + j];
    float dx = __fadd_rn(ci.x, -cj.x);
    float dy = __fadd_rn(ci.y, -cj.y);
    float d = __fsqrt_rn(__fadd_rn(__fmul_rn(dx, dx), __fmul_rn(dy, dy)));
    if (j == i) d = SELF_D;
    dv[c] = d;
  }

  for (int s = 0; s < k; ++s) {
    // local lexicographic min (ascending c => strict < keeps smallest index on ties)
    float bv = FLT_MAX;
    int bj = 1 << 30;
#pragma unroll
    for (int c = 0; c < 8; ++c) {
      int j = c * 64 + lane;
      if (dv[c] < bv) { bv = dv[c]; bj = j; }
    }
    // wave butterfly argmin, tie -> smaller index
#pragma unroll
    for (int off = 1; off < 64; off <<= 1) {
      float ov = __shfl_xor(bv, off, 64);
      int oj = __shfl_xor(bj, off, 64);
      if (ov < bv || (ov == bv && oj < bj)) { bv = ov; bj = oj; }
    }
    if (lane == 0) idxout[(size_t)row * MAXK + s] = (unsigned short)bj;
    // remove winner from its owner lane
#pragma unroll
    for (int c = 0; c < 8; ++c) {
      if (c * 64 + lane == bj) dv[c] = FLT_MAX;
    }
  }
}

// ---------------------------------------------------------------------------
// Kernel 4: fused similarity + sparse softmax + neighbor context + concat.
// One wave per output row. context = c0*S + sum_valid (c_s - c0) * e_j
//   with c_s = exp(sim_s - M)/Z, c0 = exp(-M)/Z,
//   Z = (512 - m)*exp(-M) + sum_valid exp(sim_s - M), M = max(0, max valid sim).
// ---------------------------------------------------------------------------
__global__ __launch_bounds__(256) void fuse_kernel(const float4* __restrict__ e4,
                                                   const int* __restrict__ mask,
                                                   const float4* __restrict__ S4,
                                                   const unsigned short* __restrict__ idxbuf,
                                                   const int* __restrict__ kptr,
                                                   float4* __restrict__ out4) {
  int wid = threadIdx.x >> 6;
  int lane = threadIdx.x & 63;
  int row = blockIdx.x * 4 + wid;
  int b = row >> 9;
  int k = *kptr; if (k > MAXK) k = MAXK; if (k < 0) k = 0;

  // load own row
  const float4* erow = e4 + (size_t)row * H4;
  float4 ei[3];
#pragma unroll
  for (int q = 0; q < 3; ++q) ei[q] = erow[q * 64 + lane];

  float4 ej[MAXK][3];
  float d[MAXK];
  int valid[MAXK];

#pragma unroll
  for (int s = 0; s < MAXK; ++s) {
    d[s] = 0.f;
    valid[s] = 0;
    if (s < k) {                              // wave-uniform branch
      int j = (int)idxbuf[(size_t)row * MAXK + s];
      valid[s] = (mask[b * NN + j] != 0);
      const float4* ero = e4 + ((size_t)(b * NN + j)) * H4;
      float p = 0.f;
#pragma unroll
      for (int q = 0; q < 3; ++q) {
        float4 v = ero[q * 64 + lane];
        ej[s][q] = v;
        p = fmaf(ei[q].x, v.x, p);
        p = fmaf(ei[q].y, v.y, p);
        p = fmaf(ei[q].z, v.z, p);
        p = fmaf(ei[q].w, v.w, p);
      }
      // 64-lane tree sum (all lanes end with the full dot)
#pragma unroll
      for (int off = 1; off < 64; off <<= 1) p += __shfl_xor(p, off, 64);
      d[s] = p;
    }
  }

  // softmax closed form
  float M = 0.f;
  int m = 0;
#pragma unroll
  for (int s = 0; s < MAXK; ++s) {
    if (valid[s]) { m++; if (d[s] > M) M = d[s]; }
  }
  float e0 = expf(-M);
  float Z = (float)(NN - m) * e0;
  float es[MAXK];
#pragma unroll
  for (int s = 0; s < MAXK; ++s) {
    es[s] = 0.f;
    if (valid[s]) { es[s] = expf(d[s] - M); Z += es[s]; }
  }
  float invZ = 1.0f / Z;
  float c0 = e0 * invZ;

  // context = c0*S + sum_valid (c_s - c0)*e_j
  float4 ctx[3];
#pragma unroll
  for (int q = 0; q < 3; ++q) {
    float4 Sv = S4[b * H4 + q * 64 + lane];
    ctx[q].x = c0 * Sv.x; ctx[q].y = c0 * Sv.y; ctx[q].z = c0 * Sv.z; ctx[q].w = c0 * Sv.w;
  }
#pragma unroll
  for (int s = 0; s < MAXK; ++s) {
    if (valid[s]) {                           // wave-uniform
      float cs = es[s] * invZ - c0;
#pragma unroll
      for (int q = 0; q < 3; ++q) {
        ctx[q].x = fmaf(cs, ej[s][q].x, ctx[q].x);
        ctx[q].y = fmaf(cs, ej[s][q].y, ctx[q].y);
        ctx[q].z = fmaf(cs, ej[s][q].z, ctx[q].z);
        ctx[q].w = fmaf(cs, ej[s][q].w, ctx[q].w);
      }
    }
  }

  // store [e_i | ctx]
  size_t ob = (size_t)row * (2 * H4);
#pragma unroll
  for (int q = 0; q < 3; ++q) out4[ob + q * 64 + lane] = ei[q];
#pragma unroll
  for (int q = 0; q < 3; ++q) out4[ob + H4 + q * 64 + lane] = ctx[q];
}

// ---------------------------------------------------------------------------
extern "C" void kernel_launch(void* const* d_in, const int* in_sizes, int n_in,
                              void* d_out, int out_size, void* d_ws, size_t ws_size,
                              hipStream_t stream) {
  const float* encI = (const float*)d_in[0];
  const int* RoI_mask = (const int*)d_in[1];
  const float* spatials = (const float*)d_in[2];
  const int* kptr = (const int*)d_in[3];
  float* out = (float*)d_out;

  // ws layout (small): S4 (NB*H4 float4 = 98304 B), idx (ROWS*MAXK u16 = 262144 B)
  float4* S4 = (float4*)d_ws;
  unsigned short* idxbuf = (unsigned short*)((char*)d_ws + (size_t)NB * H4 * sizeof(float4));

  // big scratch lives in the FRONT of d_out (fully overwritten by fuse_kernel later,
  // stream-ordered): partials at byte 0 (1.5 MB), centers at byte 2 MiB (128 KB).
  float4* part = (float4*)d_out;
  float2* ctr = (float2*)((char*)d_out + (2u << 20));

  centers_kernel<<<ROWS / 256, 256, 0, stream>>>(spatials, RoI_mask, ctr);
  rowsum_part_kernel<<<(NB * 16 * H4) / 256, 256, 0, stream>>>((const float4*)encI, part);
  rowsum_reduce_kernel<<<(NB * H4) / 256, 256, 0, stream>>>(part, S4);
  topk_kernel<<<ROWS / 4, 256, 0, stream>>>(ctr, kptr, idxbuf);
  fuse_kernel<<<ROWS / 4, 256, 0, stream>>>((const float4*)encI, RoI_mask, S4, idxbuf, kptr,
                                            (float4*)d_out);
  (void)in_sizes; (void)n_in; (void)out_size; (void)ws_size;
}

// Round 2
// 54.053 us; speedup vs baseline: 1.6306x; 1.6306x over previous
//
#include <hip/hip_runtime.h>
#include <cfloat>
#include <cstddef>

// Problem constants (fixed by setup_inputs): B=32, n=512, H=768, k=5
#define NB 32
#define NN 512
#define NH 768
#define H4 (NH / 4)        // 192 float4 per encI row
#define ROWS (NB * NN)     // 16384
#define MAXK 8
#define INF_C 3000.0f
#define SELF_D 9000000.0f  // INF*INF self-distance

typedef float f32x4 __attribute__((ext_vector_type(4)));

__device__ __forceinline__ void nt_store4(float4* p, float4 v) {
  f32x4 t; t.x = v.x; t.y = v.y; t.z = v.z; t.w = v.w;
  __builtin_nontemporal_store(t, (f32x4*)p);
}

// ---------------------------------------------------------------------------
// Kernel 1: blocks [0,1536): row-sum partials (64 chunks x 8 rows per batch)
//           blocks [1536,1600): adjusted box centers
// part layout: [(b*64 + chunk)][h4] (float4);  ctr: (B*n) float2
// ---------------------------------------------------------------------------
__global__ __launch_bounds__(256) void prep_kernel(const float* __restrict__ sp,
                                                   const int* __restrict__ mask,
                                                   const float4* __restrict__ e4,
                                                   float2* __restrict__ ctr,
                                                   float4* __restrict__ part) {
  int bid = blockIdx.x;
  if (bid < 1536) {
    int t = bid * 256 + threadIdx.x;          // [0, NB*64*H4) = [0, 393216)
    int h4 = t % H4;
    int bc = t / H4;
    int b = bc >> 6, chunk = bc & 63;
    const float4* p = e4 + ((size_t)(b * NN + chunk * 8)) * H4 + h4;
    float ax = 0.f, ay = 0.f, az = 0.f, aw = 0.f;
#pragma unroll
    for (int r = 0; r < 8; ++r) {
      float4 v = p[(size_t)r * H4];
      ax += v.x; ay += v.y; az += v.z; aw += v.w;
    }
    part[t] = make_float4(ax, ay, az, aw);
  } else {
    int t = (bid - 1536) * 256 + threadIdx.x; // [0, ROWS)
    const float* s = sp + (size_t)t * 6;
    float cx = __fmul_rn(__fadd_rn(s[0], s[2]), 0.5f);
    float cy = __fmul_rn(__fadd_rn(s[1], s[3]), 0.5f);
    if (mask[t] == 0) { cx = __fadd_rn(cx, INF_C); cy = __fadd_rn(cy, INF_C); }
    ctr[t] = make_float2(cx, cy);
  }
}

// ---------------------------------------------------------------------------
// Kernel 2: reduce 64 chunk-partials -> S[b][h4]
// ---------------------------------------------------------------------------
__global__ __launch_bounds__(256) void rowsum_reduce_kernel(const float4* __restrict__ part,
                                                            float4* __restrict__ S4) {
  int t = blockIdx.x * 256 + threadIdx.x;     // NB*H4 = 6144
  int h4 = t % H4;
  int b = t / H4;
  float ax = 0.f, ay = 0.f, az = 0.f, aw = 0.f;
#pragma unroll
  for (int c = 0; c < 64; ++c) {
    float4 v = part[(size_t)(b * 64 + c) * H4 + h4];
    ax += v.x; ay += v.y; az += v.z; aw += v.w;
  }
  S4[t] = make_float4(ax, ay, az, aw);
}

// ---------------------------------------------------------------------------
// Top-k nearest selection (one wave, row i of batch b). Each lane owns 8
// candidates; k rounds of lexicographic wave-argmin (ties -> smaller index,
// matching jax.lax.top_k). All lanes end up knowing sel[s].
// ---------------------------------------------------------------------------
template <int K>
__device__ __forceinline__ void topk_sel(const float2* __restrict__ ctr, int b, int i, int lane,
                                         int (&sel)[K]) {
  float2 ci = ctr[b * NN + i];
  float dv[8];
#pragma unroll
  for (int c = 0; c < 8; ++c) {
    int j = c * 64 + lane;
    float2 cj = ctr[b * NN + j];
    float dx = __fadd_rn(ci.x, -cj.x);
    float dy = __fadd_rn(ci.y, -cj.y);
    float d = __fsqrt_rn(__fadd_rn(__fmul_rn(dx, dx), __fmul_rn(dy, dy)));
    dv[c] = (j == i) ? SELF_D : d;
  }
#pragma unroll
  for (int s = 0; s < K; ++s) {
    float bv = FLT_MAX;
    int bj = 1 << 30;
#pragma unroll
    for (int c = 0; c < 8; ++c) {
      int j = c * 64 + lane;
      if (dv[c] < bv) { bv = dv[c]; bj = j; }
    }
#pragma unroll
    for (int off = 1; off < 64; off <<= 1) {
      float ov = __shfl_xor(bv, off, 64);
      int oj = __shfl_xor(bj, off, 64);
      if (ov < bv || (ov == bv && oj < bj)) { bv = ov; bj = oj; }
    }
    sel[s] = bj;
#pragma unroll
    for (int c = 0; c < 8; ++c)
      if (c * 64 + lane == bj) dv[c] = FLT_MAX;
  }
}

// ---------------------------------------------------------------------------
// Fast path, compile-time K: topk + gather + dots + sparse softmax + context.
// context = c0*S + sum_valid (c_s - c0) * e_j,
//   c_s = exp(sim_s - M)/Z, c0 = exp(-M)/Z,
//   Z = (512 - m)*exp(-M) + sum_valid exp(sim_s - M), M = max(0, max valid sim)
// ---------------------------------------------------------------------------
template <int K>
__device__ __forceinline__ void fuse_fast(const float2* __restrict__ ctr,
                                          const float4* __restrict__ e4,
                                          const int* __restrict__ mask,
                                          const float4* __restrict__ S4,
                                          float4* __restrict__ out4,
                                          int row, int b, int i, int lane) {
  int sel[K];
  topk_sel<K>(ctr, b, i, lane, sel);

  // issue all loads up-front (own row, K neighbor rows, batch sum, masks)
  const float4* erow = e4 + (size_t)row * H4;
  float4 ei[3];
#pragma unroll
  for (int q = 0; q < 3; ++q) ei[q] = erow[q * 64 + lane];

  int valid[K];
  float4 ej[K][3];
#pragma unroll
  for (int s = 0; s < K; ++s) {
    valid[s] = mask[b * NN + sel[s]];
    const float4* ero = e4 + (size_t)(b * NN + sel[s]) * H4;
#pragma unroll
    for (int q = 0; q < 3; ++q) ej[s][q] = ero[q * 64 + lane];
  }
  float4 Sv[3];
#pragma unroll
  for (int q = 0; q < 3; ++q) Sv[q] = S4[b * H4 + q * 64 + lane];

  // dot products (64-lane butterfly; all lanes end with the full dot)
  float d[K];
#pragma unroll
  for (int s = 0; s < K; ++s) {
    float p = 0.f;
#pragma unroll
    for (int q = 0; q < 3; ++q) {
      p = fmaf(ei[q].x, ej[s][q].x, p);
      p = fmaf(ei[q].y, ej[s][q].y, p);
      p = fmaf(ei[q].z, ej[s][q].z, p);
      p = fmaf(ei[q].w, ej[s][q].w, p);
    }
#pragma unroll
    for (int off = 1; off < 64; off <<= 1) p += __shfl_xor(p, off, 64);
    d[s] = p;
  }

  // sparse softmax closed form
  float M = 0.f;
  int m = 0;
#pragma unroll
  for (int s = 0; s < K; ++s)
    if (valid[s]) { ++m; M = fmaxf(M, d[s]); }
  float e0 = expf(-M);
  float Z = (float)(NN - m) * e0;
  float es[K];
#pragma unroll
  for (int s = 0; s < K; ++s) {
    es[s] = valid[s] ? expf(d[s] - M) : 0.f;
    Z += es[s];
  }
  float invZ = 1.0f / Z;
  float c0 = e0 * invZ;

  float4 ctx[3];
#pragma unroll
  for (int q = 0; q < 3; ++q) {
    ctx[q].x = c0 * Sv[q].x; ctx[q].y = c0 * Sv[q].y;
    ctx[q].z = c0 * Sv[q].z; ctx[q].w = c0 * Sv[q].w;
  }
#pragma unroll
  for (int s = 0; s < K; ++s) {
    if (valid[s]) {                            // wave-uniform
      float cs = es[s] * invZ - c0;
#pragma unroll
      for (int q = 0; q < 3; ++q) {
        ctx[q].x = fmaf(cs, ej[s][q].x, ctx[q].x);
        ctx[q].y = fmaf(cs, ej[s][q].y, ctx[q].y);
        ctx[q].z = fmaf(cs, ej[s][q].z, ctx[q].z);
        ctx[q].w = fmaf(cs, ej[s][q].w, ctx[q].w);
      }
    }
  }

  size_t ob = (size_t)row * (2 * H4);
#pragma unroll
  for (int q = 0; q < 3; ++q) nt_store4(out4 + ob + q * 64 + lane, ei[q]);
#pragma unroll
  for (int q = 0; q < 3; ++q) nt_store4(out4 + ob + H4 + q * 64 + lane, ctx[q]);
}

// Generic fallback for k != 5 (reloads gathers in phase 2; small register use).
__device__ void fuse_generic(const float2* __restrict__ ctr, const float4* __restrict__ e4,
                             const int* __restrict__ mask, const float4* __restrict__ S4,
                             float4* __restrict__ out4, int row, int b, int i, int lane, int k) {
  float2 ci = ctr[b * NN + i];
  float dv[8];
#pragma unroll
  for (int c = 0; c < 8; ++c) {
    int j = c * 64 + lane;
    float2 cj = ctr[b * NN + j];
    float dx = __fadd_rn(ci.x, -cj.x);
    float dy = __fadd_rn(ci.y, -cj.y);
    float d = __fsqrt_rn(__fadd_rn(__fmul_rn(dx, dx), __fmul_rn(dy, dy)));
    dv[c] = (j == i) ? SELF_D : d;
  }
  const float4* erow = e4 + (size_t)row * H4;
  float4 ei[3];
#pragma unroll
  for (int q = 0; q < 3; ++q) ei[q] = erow[q * 64 + lane];

  int sel[MAXK], valid[MAXK];
  float d[MAXK];
  for (int s = 0; s < k; ++s) {
    float bv = FLT_MAX;
    int bj = 1 << 30;
#pragma unroll
    for (int c = 0; c < 8; ++c) {
      int j = c * 64 + lane;
      if (dv[c] < bv) { bv = dv[c]; bj = j; }
    }
#pragma unroll
    for (int off = 1; off < 64; off <<= 1) {
      float ov = __shfl_xor(bv, off, 64);
      int oj = __shfl_xor(bj, off, 64);
      if (ov < bv || (ov == bv && oj < bj)) { bv = ov; bj = oj; }
    }
    sel[s] = bj;
#pragma unroll
    for (int c = 0; c < 8; ++c)
      if (c * 64 + lane == bj) dv[c] = FLT_MAX;
    valid[s] = mask[b * NN + bj];
    const float4* ero = e4 + (size_t)(b * NN + bj) * H4;
    float p = 0.f;
#pragma unroll
    for (int q = 0; q < 3; ++q) {
      float4 v = ero[q * 64 + lane];
      p = fmaf(ei[q].x, v.x, p);
      p = fmaf(ei[q].y, v.y, p);
      p = fmaf(ei[q].z, v.z, p);
      p = fmaf(ei[q].w, v.w, p);
    }
#pragma unroll
    for (int off = 1; off < 64; off <<= 1) p += __shfl_xor(p, off, 64);
    d[s] = p;
  }
  float M = 0.f;
  int m = 0;
  for (int s = 0; s < k; ++s)
    if (valid[s]) { ++m; M = fmaxf(M, d[s]); }
  float e0 = expf(-M);
  float Z = (float)(NN - m) * e0;
  float es[MAXK];
  for (int s = 0; s < k; ++s) {
    es[s] = valid[s] ? expf(d[s] - M) : 0.f;
    Z += es[s];
  }
  float invZ = 1.0f / Z;
  float c0 = e0 * invZ;
  float4 ctx[3];
#pragma unroll
  for (int q = 0; q < 3; ++q) {
    float4 Sv = S4[b * H4 + q * 64 + lane];
    ctx[q].x = c0 * Sv.x; ctx[q].y = c0 * Sv.y; ctx[q].z = c0 * Sv.z; ctx[q].w = c0 * Sv.w;
  }
  for (int s = 0; s < k; ++s) {
    if (valid[s]) {
      float cs = es[s] * invZ - c0;
      const float4* ero = e4 + (size_t)(b * NN + sel[s]) * H4;
#pragma unroll
      for (int q = 0; q < 3; ++q) {
        float4 v = ero[q * 64 + lane];
        ctx[q].x = fmaf(cs, v.x, ctx[q].x);
        ctx[q].y = fmaf(cs, v.y, ctx[q].y);
        ctx[q].z = fmaf(cs, v.z, ctx[q].z);
        ctx[q].w = fmaf(cs, v.w, ctx[q].w);
      }
    }
  }
  size_t ob = (size_t)row * (2 * H4);
#pragma unroll
  for (int q = 0; q < 3; ++q) nt_store4(out4 + ob + q * 64 + lane, ei[q]);
#pragma unroll
  for (int q = 0; q < 3; ++q) nt_store4(out4 + ob + H4 + q * 64 + lane, ctx[q]);
}

// ---------------------------------------------------------------------------
// Kernel 3: fused topk + similarity + sparse softmax + context + concat.
// One wave per output row; chunked XCD swizzle (4096 blocks, 8 XCDs).
// ---------------------------------------------------------------------------
__global__ __launch_bounds__(256) void fuse_topk_kernel(const float2* __restrict__ ctr,
                                                        const float4* __restrict__ e4,
                                                        const int* __restrict__ mask,
                                                        const float4* __restrict__ S4,
                                                        const int* __restrict__ kptr,
                                                        float4* __restrict__ out4) {
  int bid = blockIdx.x;
  int swz = (bid & 7) * (ROWS / 4 / 8) + (bid >> 3);  // bijective: 4096 % 8 == 0
  int wid = threadIdx.x >> 6;
  int lane = threadIdx.x & 63;
  int row = swz * 4 + wid;
  int b = row >> 9;
  int i = row & (NN - 1);
  int k = *kptr;
  if (k == 5) {
    fuse_fast<5>(ctr, e4, mask, S4, out4, row, b, i, lane);
  } else {
    if (k > MAXK) k = MAXK;
    if (k < 0) k = 0;
    fuse_generic(ctr, e4, mask, S4, out4, row, b, i, lane, k);
  }
}

// ---------------------------------------------------------------------------
extern "C" void kernel_launch(void* const* d_in, const int* in_sizes, int n_in,
                              void* d_out, int out_size, void* d_ws, size_t ws_size,
                              hipStream_t stream) {
  const float* encI = (const float*)d_in[0];
  const int* RoI_mask = (const int*)d_in[1];
  const float* spatials = (const float*)d_in[2];
  const int* kptr = (const int*)d_in[3];

  // ws layout: ctr (ROWS float2 = 128 KB) @0, S4 (NB*H4 float4 = 96 KB) @128K
  float2* ctr = (float2*)d_ws;
  float4* S4 = (float4*)((char*)d_ws + (size_t)ROWS * sizeof(float2));

  // big scratch (rowsum partials, 6 MB) in the FRONT of d_out — written by K1,
  // read by K2, fully overwritten by K3 later (stream-ordered).
  float4* part = (float4*)d_out;

  prep_kernel<<<1600, 256, 0, stream>>>(spatials, RoI_mask, (const float4*)encI, ctr, part);
  rowsum_reduce_kernel<<<24, 256, 0, stream>>>(part, S4);
  fuse_topk_kernel<<<ROWS / 4, 256, 0, stream>>>(ctr, (const float4*)encI, RoI_mask, S4, kptr,
                                                 (float4*)d_out);
  (void)in_sizes; (void)n_in; (void)out_size; (void)ws_size;
}